// Round 16
// baseline (3954.374 us; speedup 1.0000x reference)
//
#include <hip/hip_runtime.h>

typedef unsigned short u16;
typedef unsigned int u32;
typedef __attribute__((ext_vector_type(8))) short bf16x8;
typedef __attribute__((ext_vector_type(4))) float f32x4;
typedef __attribute__((ext_vector_type(4))) u32 u32x4;
typedef const __attribute__((address_space(1))) void* gas1_t;
typedef __attribute__((address_space(3))) void* las3_t;

// Problem dims
#define T_LEN 512
#define B_SZ  64
#define D_SZ  1024
#define H_SZ  1024

// workspace layout (bytes), all 256-aligned
#define OFF_WX    0UL           // 8 MiB  bf16 Wx  [4096][1024]
#define OFF_WH    8388608UL     // 8 MiB  bf16 Wh  [4096][1024]
#define OFF_BIAS  16777216UL    // 16 KiB f32 bias[4096] = bx+bh
#define OFF_FLAGS 16793600UL    // 2 KiB: cnt0 @+0, cnt1 @+256 (lstm barrier); cnt_x[256] @+1024 (gemm slab counters)
#define OFF_HROLL 16795648UL    // 64 MiB bf16 hroll[512][64][1024]
#define OFF_XBF   83904512UL    // 64 MiB bf16 x [32768][1024]
#define OFF_XPROJ 151013376UL   // 256 MiB bf16 xprojP [512][gate(4)][hs(128)][brow(64)][jj(8)]

__device__ __forceinline__ u16 f2bf(float f) {
  u32 u = __builtin_bit_cast(u32, f);
  u += 0x7FFFu + ((u >> 16) & 1u);   // RNE
  return (u16)(u >> 16);
}
__device__ __forceinline__ float bf2f(u16 h) {
  u32 u = ((u32)h) << 16;
  return __builtin_bit_cast(float, u);
}

// ---------- phase 0: conversions ----------
__global__ __launch_bounds__(256) void cvt_f32_bf16(const float* __restrict__ in,
                                                    u16* __restrict__ out, int n) {
  int i = (blockIdx.x * 256 + threadIdx.x) * 4;
  if (i >= n) return;
  float4 v = *(const float4*)(in + i);
  ushort4 o;
  o.x = f2bf(v.x); o.y = f2bf(v.y); o.z = f2bf(v.z); o.w = f2bf(v.w);
  *(ushort4*)(out + i) = o;
}

__global__ __launch_bounds__(256) void bias_add(const float* __restrict__ a,
                                                const float* __restrict__ b,
                                                float* __restrict__ o) {
  int i = blockIdx.x * 256 + threadIdx.x;  // 4096 total
  o[i] = a[i] + b[i];
}

// ---------- fused phase 1+2: producer-consumer ----------
// 256 WGs x 512 threads. WGs 0..127: lstm consumer. WGs 128..255: persistent
// gemm producer (t-major tiles, sc0sc1 epilogue stores + vmcnt(0) + atomic
// cnt_x[tp]++ publish). Consumer gates xproj prefetch on cnt_x (quad-poll,
// local watermark). xproj/hroll addresses are virgin per launch -> cached
// consumer reads are staleness-safe; replays rewrite identical values.
// R16 change: lstm waves = 2 col-groups x 4 K-slices (R8 mapping) -> reduce
// depth 8->4 (LDS traffic halves); cg-duplicated h reads are L2-cached now.
__global__ __launch_bounds__(512, 2) void lstm_fused(const u16* __restrict__ A,     // x_bf
                                                     const u16* __restrict__ Bw,    // wx_bf
                                                     u16* __restrict__ xprojP,
                                                     const u16* __restrict__ Whb,
                                                     const float* __restrict__ bias,
                                                     u16* __restrict__ hroll,
                                                     u32* __restrict__ flags,
                                                     float* __restrict__ out) {
  __shared__ __align__(16) char smem[34816];
  int wg = blockIdx.x;
  int tid = threadIdx.x;   // 0..511
  int lane = tid & 63;
  int w = tid >> 6;        // 0..7
  int hi8 = (lane >> 4) << 3;
  u32* cntx = flags + 256;  // cnt_x[256] @ byte offset +1024

  if (wg >= 128) {
    // ================= GEMM PRODUCER =================
    u16* As = (u16*)smem;              // [128][64]
    u16* Bs = (u16*)(smem + 16384);    // [128][64]
    int g = wg - 128;                  // 0..127
    int wm = w >> 1, wn = w & 1;       // wave grid 4x2 on 128x128
    int col8 = (lane & 7) * 8;
    int rowL = w * 8 + (lane >> 3);    // staging row within 64-row round

    for (int idx = g; idx < 8192; idx += 128) {
      int tp = idx >> 5;               // 0..255 (rows tp*128 = steps 2tp,2tp+1)
      int nb = idx & 31;               // col tile
      const u16* At = A + (size_t)tp * 131072;
      const u16* Bt = Bw + (size_t)nb * 131072;

      f32x4 acc[2][4];
#pragma unroll
      for (int mt = 0; mt < 2; ++mt)
#pragma unroll
        for (int nt = 0; nt < 4; ++nt) acc[mt][nt] = f32x4{0.f, 0.f, 0.f, 0.f};

      for (int k0 = 0; k0 < 1024; k0 += 64) {
#pragma unroll
        for (int r = 0; r < 2; ++r) {
          int row = r * 64 + rowL;
          int dst = r * 4096 + w * 512;
          __builtin_amdgcn_global_load_lds((gas1_t)(const void*)(At + (size_t)row * 1024 + k0 + col8),
                                           (las3_t)(void*)(&As[dst]), 16, 0, 0);
          __builtin_amdgcn_global_load_lds((gas1_t)(const void*)(Bt + (size_t)row * 1024 + k0 + col8),
                                           (las3_t)(void*)(&Bs[dst]), 16, 0, 0);
        }
        __syncthreads();
#pragma unroll
        for (int kk = 0; kk < 64; kk += 32) {
          bf16x8 af[2], bfr[4];
#pragma unroll
          for (int mt = 0; mt < 2; ++mt)
            af[mt] = *(const bf16x8*)&As[(wm * 32 + mt * 16 + (lane & 15)) * 64 + kk + hi8];
#pragma unroll
          for (int nt = 0; nt < 4; ++nt)
            bfr[nt] = *(const bf16x8*)&Bs[(wn * 64 + nt * 16 + (lane & 15)) * 64 + kk + hi8];
#pragma unroll
          for (int mt = 0; mt < 2; ++mt)
#pragma unroll
            for (int nt = 0; nt < 4; ++nt)
              acc[mt][nt] = __builtin_amdgcn_mfma_f32_16x16x32_bf16(af[mt], bfr[nt], acc[mt][nt], 0, 0, 0);
        }
        __syncthreads();
      }
      // epilogue: per-gate-plane layout, write-through stores (LLC-visible)
#pragma unroll
      for (int mt = 0; mt < 2; ++mt)
#pragma unroll
        for (int nt = 0; nt < 4; ++nt) {
          int col = nb * 128 + wn * 64 + nt * 16 + (lane & 15);
          int gate = col >> 10;
          int hc = col & 1023;
          size_t cb = (size_t)gate * 65536 + (size_t)(hc >> 3) * 512 + (hc & 7);
#pragma unroll
          for (int r = 0; r < 4; ++r) {
            int row = tp * 128 + wm * 32 + mt * 16 + ((lane >> 4) << 2) + r;
            u16* cp = xprojP + (size_t)(row >> 6) * 262144 + cb + (size_t)(row & 63) * 8;
            u32 val = (u32)f2bf(acc[mt][nt][r]);
            asm volatile("global_store_short %0, %1, off sc0 sc1" :: "v"(cp), "v"(val) : "memory");
          }
        }
      asm volatile("s_waitcnt vmcnt(0)" ::: "memory");
      __syncthreads();  // all waves' stores drained
      if (tid == 0) {
        u32 one = 1u;
        u32* cp = cntx + tp;
        asm volatile("global_atomic_add %0, %1, off" :: "v"(cp), "v"(one) : "memory");
      }
    }
    return;
  }

  // ================= LSTM CONSUMER =================
  float* pacc = (float*)smem;  // 32 frags [cg][kq][rt][cf], rows padded to 17
#define PIDX(frag, row, col) (((frag) * 272) + (row) * 17 + (col))
  int bh = wg >> 6;        // batch half (independent barrier domain)
  int hw = wg & 63;        // 16-col slice
  int cg = w >> 2;         // col-group: gates {2cg, 2cg+1}
  int kq = w & 3;          // K-slice, 0..3 (256 k-cols each)
  int kw = kq << 8;

  // Wh fragments: wf[cf][ks], gate = cg*2+cf, out-col = hw*16 + (lane&15)
  bf16x8 wf[2][8];
#pragma unroll
  for (int cf = 0; cf < 2; ++cf) {
    int wrow = ((cg * 2 + cf) << 10) + (hw << 4) + (lane & 15);
#pragma unroll
    for (int ks = 0; ks < 8; ++ks)
      wf[cf][ks] = *(const bf16x8*)&Whb[(size_t)wrow * 1024 + kw + ks * 32 + hi8];
  }

  int b = tid >> 4;
  int jj = tid & 15;
  int hrow = (bh << 5) + b;
  int hcol = (hw << 4) + jj;
  float bs0 = bias[hcol], bs1 = bias[1024 + hcol], bs2 = bias[2048 + hcol], bs3 = bias[3072 + hcol];
  float c_state = 0.f;
  int am_row0 = (bh << 5) + (lane & 15);
  int am_row1 = am_row0 + 16;
  int mI = b >> 4, r16 = b & 15;
  u32* cnt = flags + (bh << 6);

  const u16* xpt = xprojP + (size_t)(hcol >> 3) * 512 + (size_t)hrow * 8 + (hcol & 7);
  int ready_tp = 0;  // tps known complete (local watermark)

  // gate + prefetch for t=0 (slab tp=0)
  {
    const u32* cp = cntx;
    for (;;) {
      u32x4 c4;
      asm volatile("global_load_dwordx4 %0, %1, off sc0 sc1\n\ts_waitcnt vmcnt(0)"
                   : "=&v"(c4) : "v"(cp) : "memory");
      if (c4[0] >= 32u) {
        ready_tp = 1;
        if (c4[1] >= 32u) { ready_tp = 2;
          if (c4[2] >= 32u) { ready_tp = 3;
            if (c4[3] >= 32u) ready_tp = 4; } }
        break;
      }
    }
  }
  u32 px0 = xpt[0], px1 = xpt[65536], px2 = xpt[131072], px3 = xpt[196608];

  for (int t = 0; t < T_LEN; ++t) {
    // h load: NORMAL CACHED from rolling slot t (virgin addresses; cg-dup hits L2)
    const u16* hcur = hroll + (size_t)t * 65536;
    const u16* p0 = hcur + (size_t)am_row0 * 1024 + kw + hi8;
    const u16* p1 = hcur + (size_t)am_row1 * 1024 + kw + hi8;
    bf16x8 a0[8], a1[8];
#pragma unroll
    for (int ks = 0; ks < 8; ++ks) {
      a0[ks] = *(const bf16x8*)(p0 + ks * 32);
      a1[ks] = *(const bf16x8*)(p1 + ks * 32);
    }

    // MFMA: 4 accs (2 row-frags x 2 gate-frags) over 8 k-steps
    f32x4 acc00 = f32x4{0.f, 0.f, 0.f, 0.f}, acc01 = acc00, acc10 = acc00, acc11 = acc00;
#pragma unroll
    for (int ks = 0; ks < 8; ++ks) {
      acc00 = __builtin_amdgcn_mfma_f32_16x16x32_bf16(a0[ks], wf[0][ks], acc00, 0, 0, 0);
      acc01 = __builtin_amdgcn_mfma_f32_16x16x32_bf16(a0[ks], wf[1][ks], acc01, 0, 0, 0);
      acc10 = __builtin_amdgcn_mfma_f32_16x16x32_bf16(a1[ks], wf[0][ks], acc10, 0, 0, 0);
      acc11 = __builtin_amdgcn_mfma_f32_16x16x32_bf16(a1[ks], wf[1][ks], acc11, 0, 0, 0);
    }
    // per-wave partials -> LDS: frag = cg*16 + kq*4 + rt*2 + cf
    {
      int rbase = (lane >> 4) << 2;
      int cidx = lane & 15;
      int f0i = (cg << 4) + (kq << 2);
#pragma unroll
      for (int r = 0; r < 4; ++r) {
        pacc[PIDX(f0i + 0, rbase + r, cidx)] = acc00[r];
        pacc[PIDX(f0i + 1, rbase + r, cidx)] = acc01[r];
        pacc[PIDX(f0i + 2, rbase + r, cidx)] = acc10[r];
        pacc[PIDX(f0i + 3, rbase + r, cidx)] = acc11[r];
      }
    }
    __syncthreads();
    // reduce over 4 kq partials per gate
    float g[4];
#pragma unroll
    for (int f = 0; f < 4; ++f) {
      int cgg = f >> 1, cf = f & 1;
      float s = 0.f;
#pragma unroll
      for (int k2 = 0; k2 < 4; ++k2)
        s += pacc[PIDX((cgg << 4) + (k2 << 2) + (mI << 1) + cf, r16, jj)];
      g[f] = s;
    }
    asm volatile("s_waitcnt vmcnt(0)" : "+v"(px0), "+v"(px1), "+v"(px2), "+v"(px3));
    float gi = g[0] + bf2f((u16)px0) + bs0;
    float gf = g[1] + bf2f((u16)px1) + bs1;
    float go = g[2] + bf2f((u16)px2) + bs2;
    float gc = g[3] + bf2f((u16)px3) + bs3;
    float iv = 1.f / (1.f + __expf(-gi));
    float fv = 1.f / (1.f + __expf(-gf));
    float ov = 1.f / (1.f + __expf(-go));
    float cv = tanhf(gc);
    c_state = 1.f / (1.f + __expf(-(fv * c_state + iv * cv)));  // nonstandard, per reference
    float hn = tanhf(c_state) * ov;

    if (t == T_LEN - 1) {
      out[(size_t)hrow * 1024 + hcol] = hn;
    } else {
      // h store (write-through)
      u16* hdst = hroll + (size_t)(t + 1) * 65536 + (size_t)hrow * 1024 + hcol;
      u32 hb = (u32)f2bf(hn);
      asm volatile("global_store_short %0, %1, off sc0 sc1" :: "v"(hdst), "v"(hb) : "memory");
      // gate: slab for step t+1 must be published (ramp-only in steady state)
      int tpn = (t + 1) >> 1;
      if (tpn >= ready_tp) {
        const u32* cp = cntx + (tpn & ~3);
        int q = tpn & 3;
        for (;;) {
          u32x4 c4;
          asm volatile("global_load_dwordx4 %0, %1, off sc0 sc1\n\ts_waitcnt vmcnt(0)"
                       : "=&v"(c4) : "v"(cp) : "memory");
          u32 v0 = c4[0], v1 = c4[1], v2 = c4[2], v3 = c4[3];
          bool b0 = v0 >= 32u, b1 = v1 >= 32u, b2 = v2 >= 32u, b3 = v3 >= 32u;
          bool mine = (q == 0) ? b0 : (q == 1) ? b1 : (q == 2) ? b2 : b3;
          if (mine) {
            int ext = (q == 0) ? (b1 ? (b2 ? (b3 ? 4 : 3) : 2) : 1)
                    : (q == 1) ? (b2 ? (b3 ? 3 : 2) : 1)
                    : (q == 2) ? (b3 ? 2 : 1) : 1;
            ready_tp = tpn + ext;
            break;
          }
        }
      }
      // xproj(t+1) prefetch (plain cached; lines virgin -> post-publish fills)
      const u16* xn0 = xpt + (size_t)(t + 1) * 262144;
      const u16* xn1 = xn0 + 65536;
      const u16* xn2 = xn0 + 131072;
      const u16* xn3 = xn0 + 196608;
      asm volatile(
          "global_load_ushort %0, %4, off\n\t"
          "global_load_ushort %1, %5, off\n\t"
          "global_load_ushort %2, %6, off\n\t"
          "global_load_ushort %3, %7, off"
          : "=&v"(px0), "=&v"(px1), "=&v"(px2), "=&v"(px3)
          : "v"(xn0), "v"(xn1), "v"(xn2), "v"(xn3)
          : "memory");
      // retire the h store (oldest VMEM op; 4 prefetch loads stay in flight)
      asm volatile("s_waitcnt vmcnt(4)" ::: "memory");
      __syncthreads();  // all 8 waves' stores drained; pacc reads done
      if (tid == 0) {
        u32 one = 1u;
        asm volatile("global_atomic_add %0, %1, off" :: "v"(cnt), "v"(one) : "memory");
        u32 tgt = (u32)((t + 1) << 6);  // 64 publishers per domain
        u32 f;
        for (;;) {
          asm volatile("global_load_dword %0, %1, off sc0 sc1\n\ts_waitcnt vmcnt(0)"
                       : "=&v"(f) : "v"(cnt) : "memory");
          if (f >= tgt) break;
        }
      }
      __syncthreads();
    }
  }
}

extern "C" void kernel_launch(void* const* d_in, const int* in_sizes, int n_in,
                              void* d_out, int out_size, void* d_ws, size_t ws_size,
                              hipStream_t stream) {
  const float* x  = (const float*)d_in[0];   // [512][64][1024]
  const float* Wx = (const float*)d_in[1];   // [4][1024][1024]
  const float* bx = (const float*)d_in[2];   // [4][1024]
  const float* Wh = (const float*)d_in[3];   // [4][1024][1024]
  const float* bh = (const float*)d_in[4];   // [4][1024]
  float* out = (float*)d_out;                // [64][1024]
  char* ws = (char*)d_ws;

  u16* wx_bf  = (u16*)(ws + OFF_WX);
  u16* wh_bf  = (u16*)(ws + OFF_WH);
  float* bias = (float*)(ws + OFF_BIAS);
  u32* flags  = (u32*)(ws + OFF_FLAGS);
  u16* hroll  = (u16*)(ws + OFF_HROLL);
  u16* x_bf   = (u16*)(ws + OFF_XBF);
  u16* xproj  = (u16*)(ws + OFF_XPROJ);

  // per-launch: zero barrier counters + slab counters (2 KiB) + hroll slot 0
  // (128 KiB) -- contiguous region
  hipMemsetAsync(ws + OFF_FLAGS, 0, 2048 + 131072, stream);

  cvt_f32_bf16<<<4096, 256, 0, stream>>>(Wx, wx_bf, 4194304);
  cvt_f32_bf16<<<4096, 256, 0, stream>>>(Wh, wh_bf, 4194304);
  bias_add<<<16, 256, 0, stream>>>(bx, bh, bias);
  cvt_f32_bf16<<<32768, 256, 0, stream>>>(x, x_bf, 33554432);
  lstm_fused<<<256, 512, 0, stream>>>(x_bf, wx_bf, xproj, wh_bf, bias, hroll, flags, out);
}

// Round 17
// 2864.741 us; speedup vs baseline: 1.3804x; 1.3804x over previous
//
#include <hip/hip_runtime.h>

typedef unsigned short u16;
typedef unsigned int u32;
typedef __attribute__((ext_vector_type(8))) short bf16x8;
typedef __attribute__((ext_vector_type(4))) float f32x4;
typedef __attribute__((ext_vector_type(4))) u32 u32x4;
typedef const __attribute__((address_space(1))) void* gas1_t;
typedef __attribute__((address_space(3))) void* las3_t;

// Problem dims
#define T_LEN 512
#define B_SZ  64
#define D_SZ  1024
#define H_SZ  1024

// workspace layout (bytes), all 256-aligned
#define OFF_WX    0UL           // 8 MiB  bf16 Wx  [4096][1024]
#define OFF_WH    8388608UL     // 8 MiB  bf16 Wh  [4096][1024]
#define OFF_BIAS  16777216UL    // 16 KiB f32 bias[4096] = bx+bh
#define OFF_FLAGS 16793600UL    // 2 KiB: cnt0 @+0, cnt1 @+256 (lstm barrier); cnt_x[256] @+1024 (gemm slab counters)
#define OFF_HROLL 16795648UL    // 64 MiB bf16 hroll[512][64][1024]
#define OFF_XBF   83904512UL    // 64 MiB bf16 x [32768][1024]
#define OFF_XPROJ 151013376UL   // 256 MiB bf16 xprojP [512][gate(4)][hs(128)][brow(64)][jj(8)]

__device__ __forceinline__ u16 f2bf(float f) {
  u32 u = __builtin_bit_cast(u32, f);
  u += 0x7FFFu + ((u >> 16) & 1u);   // RNE
  return (u16)(u >> 16);
}
__device__ __forceinline__ float bf2f(u16 h) {
  u32 u = ((u32)h) << 16;
  return __builtin_bit_cast(float, u);
}

// ---------- phase 0: conversions ----------
__global__ __launch_bounds__(256) void cvt_f32_bf16(const float* __restrict__ in,
                                                    u16* __restrict__ out, int n) {
  int i = (blockIdx.x * 256 + threadIdx.x) * 4;
  if (i >= n) return;
  float4 v = *(const float4*)(in + i);
  ushort4 o;
  o.x = f2bf(v.x); o.y = f2bf(v.y); o.z = f2bf(v.z); o.w = f2bf(v.w);
  *(ushort4*)(out + i) = o;
}

__global__ __launch_bounds__(256) void bias_add(const float* __restrict__ a,
                                                const float* __restrict__ b,
                                                float* __restrict__ o) {
  int i = blockIdx.x * 256 + threadIdx.x;  // 4096 total
  o[i] = a[i] + b[i];
}

// ---------- fused phase 1+2: producer-consumer (R15, best known) ----------
// 256 WGs x 512 threads. WGs 0..127: lstm consumer (8-way K-partition).
// WGs 128..255: persistent gemm producer -- t-major tiles, sc0sc1 epilogue
// stores + vmcnt(0) + atomic cnt_x[tp]++ publish. Consumer gates its xproj
// prefetch on cnt_x[tp]==32 (quad-poll, local watermark). xproj/hroll
// addresses are virgin per launch -> cached consumer reads are
// staleness-safe; replays rewrite identical values.
__global__ __launch_bounds__(512, 2) void lstm_fused(const u16* __restrict__ A,     // x_bf
                                                     const u16* __restrict__ Bw,    // wx_bf
                                                     u16* __restrict__ xprojP,
                                                     const u16* __restrict__ Whb,
                                                     const float* __restrict__ bias,
                                                     u16* __restrict__ hroll,
                                                     u32* __restrict__ flags,
                                                     float* __restrict__ out) {
  __shared__ __align__(16) char smem[69632];
  int wg = blockIdx.x;
  int tid = threadIdx.x;   // 0..511
  int lane = tid & 63;
  int w = tid >> 6;        // 0..7
  int hi8 = (lane >> 4) << 3;
  u32* cntx = flags + 256;  // cnt_x[256] @ byte offset +1024

  if (wg >= 128) {
    // ================= GEMM PRODUCER =================
    u16* As = (u16*)smem;              // [128][64]
    u16* Bs = (u16*)(smem + 16384);    // [128][64]
    int g = wg - 128;                  // 0..127
    int wm = w >> 1, wn = w & 1;       // wave grid 4x2 on 128x128
    int col8 = (lane & 7) * 8;
    int rowL = w * 8 + (lane >> 3);    // staging row within 64-row round

    for (int idx = g; idx < 8192; idx += 128) {
      int tp = idx >> 5;               // 0..255 (rows tp*128 = steps 2tp,2tp+1)
      int nb = idx & 31;               // col tile
      const u16* At = A + (size_t)tp * 131072;
      const u16* Bt = Bw + (size_t)nb * 131072;

      f32x4 acc[2][4];
#pragma unroll
      for (int mt = 0; mt < 2; ++mt)
#pragma unroll
        for (int nt = 0; nt < 4; ++nt) acc[mt][nt] = f32x4{0.f, 0.f, 0.f, 0.f};

      for (int k0 = 0; k0 < 1024; k0 += 64) {
#pragma unroll
        for (int r = 0; r < 2; ++r) {
          int row = r * 64 + rowL;
          int dst = r * 4096 + w * 512;  // + lane*8 implicit (wave-uniform base)
          __builtin_amdgcn_global_load_lds((gas1_t)(const void*)(At + (size_t)row * 1024 + k0 + col8),
                                           (las3_t)(void*)(&As[dst]), 16, 0, 0);
          __builtin_amdgcn_global_load_lds((gas1_t)(const void*)(Bt + (size_t)row * 1024 + k0 + col8),
                                           (las3_t)(void*)(&Bs[dst]), 16, 0, 0);
        }
        __syncthreads();
#pragma unroll
        for (int kk = 0; kk < 64; kk += 32) {
          bf16x8 af[2], bfr[4];
#pragma unroll
          for (int mt = 0; mt < 2; ++mt)
            af[mt] = *(const bf16x8*)&As[(wm * 32 + mt * 16 + (lane & 15)) * 64 + kk + hi8];
#pragma unroll
          for (int nt = 0; nt < 4; ++nt)
            bfr[nt] = *(const bf16x8*)&Bs[(wn * 64 + nt * 16 + (lane & 15)) * 64 + kk + hi8];
#pragma unroll
          for (int mt = 0; mt < 2; ++mt)
#pragma unroll
            for (int nt = 0; nt < 4; ++nt)
              acc[mt][nt] = __builtin_amdgcn_mfma_f32_16x16x32_bf16(af[mt], bfr[nt], acc[mt][nt], 0, 0, 0);
        }
        __syncthreads();
      }
      // epilogue: per-gate-plane layout, write-through stores (LLC-visible)
#pragma unroll
      for (int mt = 0; mt < 2; ++mt)
#pragma unroll
        for (int nt = 0; nt < 4; ++nt) {
          int col = nb * 128 + wn * 64 + nt * 16 + (lane & 15);
          int gate = col >> 10;
          int hc = col & 1023;
          size_t cb = (size_t)gate * 65536 + (size_t)(hc >> 3) * 512 + (hc & 7);
#pragma unroll
          for (int r = 0; r < 4; ++r) {
            int row = tp * 128 + wm * 32 + mt * 16 + ((lane >> 4) << 2) + r;
            u16* cp = xprojP + (size_t)(row >> 6) * 262144 + cb + (size_t)(row & 63) * 8;
            u32 val = (u32)f2bf(acc[mt][nt][r]);
            asm volatile("global_store_short %0, %1, off sc0 sc1" :: "v"(cp), "v"(val) : "memory");
          }
        }
      asm volatile("s_waitcnt vmcnt(0)" ::: "memory");
      __syncthreads();  // all waves' stores drained
      if (tid == 0) {
        u32 one = 1u;
        u32* cp = cntx + tp;
        asm volatile("global_atomic_add %0, %1, off" :: "v"(cp), "v"(one) : "memory");
      }
    }
    return;
  }

  // ================= LSTM CONSUMER (R14 structure) =================
  float* pacc = (float*)smem;  // 64 frags [kq][rt][f], rows padded to 17
#define PIDX(frag, row, col) (((frag) * 272) + (row) * 17 + (col))
  int bh = wg >> 6;        // batch half (independent barrier domain)
  int hw = wg & 63;        // 16-col slice
  int kq = w;              // wave = K-slice, 0..7 (128 k-cols each)
  int kw = kq << 7;

  bf16x8 wf[4][4];
#pragma unroll
  for (int f = 0; f < 4; ++f) {
    int wrow = (f << 10) + (hw << 4) + (lane & 15);
#pragma unroll
    for (int ks = 0; ks < 4; ++ks)
      wf[f][ks] = *(const bf16x8*)&Whb[(size_t)wrow * 1024 + kw + ks * 32 + hi8];
  }

  int b = tid >> 4;
  int jj = tid & 15;
  int hrow = (bh << 5) + b;
  int hcol = (hw << 4) + jj;
  float bs0 = bias[hcol], bs1 = bias[1024 + hcol], bs2 = bias[2048 + hcol], bs3 = bias[3072 + hcol];
  float c_state = 0.f;
  int am_row0 = (bh << 5) + (lane & 15);
  int am_row1 = am_row0 + 16;
  int mI = b >> 4, r16 = b & 15;
  u32* cnt = flags + (bh << 6);

  const u16* xpt = xprojP + (size_t)(hcol >> 3) * 512 + (size_t)hrow * 8 + (hcol & 7);
  int ready_tp = 0;  // tps known complete (local watermark)

  // gate + prefetch for t=0 (slab tp=0)
  {
    const u32* cp = cntx;  // quad base 0
    for (;;) {
      u32x4 c4;
      asm volatile("global_load_dwordx4 %0, %1, off sc0 sc1\n\ts_waitcnt vmcnt(0)"
                   : "=&v"(c4) : "v"(cp) : "memory");
      if (c4[0] >= 32u) {
        ready_tp = 1;
        if (c4[1] >= 32u) { ready_tp = 2;
          if (c4[2] >= 32u) { ready_tp = 3;
            if (c4[3] >= 32u) ready_tp = 4; } }
        break;
      }
    }
  }
  u32 px0 = xpt[0], px1 = xpt[65536], px2 = xpt[131072], px3 = xpt[196608];

  for (int t = 0; t < T_LEN; ++t) {
    // h load: NORMAL CACHED from rolling slot t (virgin addresses)
    const u16* hcur = hroll + (size_t)t * 65536;
    const u16* p0 = hcur + (size_t)am_row0 * 1024 + kw + hi8;
    const u16* p1 = hcur + (size_t)am_row1 * 1024 + kw + hi8;
    bf16x8 a0[4], a1[4];
#pragma unroll
    for (int ks = 0; ks < 4; ++ks) {
      a0[ks] = *(const bf16x8*)(p0 + ks * 32);
      a1[ks] = *(const bf16x8*)(p1 + ks * 32);
    }

    f32x4 acc00 = f32x4{0.f, 0.f, 0.f, 0.f}, acc01 = acc00, acc02 = acc00, acc03 = acc00;
    f32x4 acc10 = acc00, acc11 = acc00, acc12 = acc00, acc13 = acc00;
#pragma unroll
    for (int ks = 0; ks < 4; ++ks) {
      acc00 = __builtin_amdgcn_mfma_f32_16x16x32_bf16(a0[ks], wf[0][ks], acc00, 0, 0, 0);
      acc01 = __builtin_amdgcn_mfma_f32_16x16x32_bf16(a0[ks], wf[1][ks], acc01, 0, 0, 0);
      acc02 = __builtin_amdgcn_mfma_f32_16x16x32_bf16(a0[ks], wf[2][ks], acc02, 0, 0, 0);
      acc03 = __builtin_amdgcn_mfma_f32_16x16x32_bf16(a0[ks], wf[3][ks], acc03, 0, 0, 0);
      acc10 = __builtin_amdgcn_mfma_f32_16x16x32_bf16(a1[ks], wf[0][ks], acc10, 0, 0, 0);
      acc11 = __builtin_amdgcn_mfma_f32_16x16x32_bf16(a1[ks], wf[1][ks], acc11, 0, 0, 0);
      acc12 = __builtin_amdgcn_mfma_f32_16x16x32_bf16(a1[ks], wf[2][ks], acc12, 0, 0, 0);
      acc13 = __builtin_amdgcn_mfma_f32_16x16x32_bf16(a1[ks], wf[3][ks], acc13, 0, 0, 0);
    }
    {
      int rbase = (lane >> 4) << 2;
      int cidx = lane & 15;
      int f0i = kq << 3;
#pragma unroll
      for (int r = 0; r < 4; ++r) {
        pacc[PIDX(f0i + 0, rbase + r, cidx)] = acc00[r];
        pacc[PIDX(f0i + 1, rbase + r, cidx)] = acc01[r];
        pacc[PIDX(f0i + 2, rbase + r, cidx)] = acc02[r];
        pacc[PIDX(f0i + 3, rbase + r, cidx)] = acc03[r];
        pacc[PIDX(f0i + 4, rbase + r, cidx)] = acc10[r];
        pacc[PIDX(f0i + 5, rbase + r, cidx)] = acc11[r];
        pacc[PIDX(f0i + 6, rbase + r, cidx)] = acc12[r];
        pacc[PIDX(f0i + 7, rbase + r, cidx)] = acc13[r];
      }
    }
    __syncthreads();
    float g[4];
#pragma unroll
    for (int f = 0; f < 4; ++f) {
      float s = 0.f;
#pragma unroll
      for (int k2 = 0; k2 < 8; ++k2)
        s += pacc[PIDX((k2 << 3) + (mI << 2) + f, r16, jj)];
      g[f] = s;
    }
    asm volatile("s_waitcnt vmcnt(0)" : "+v"(px0), "+v"(px1), "+v"(px2), "+v"(px3));
    float gi = g[0] + bf2f((u16)px0) + bs0;
    float gf = g[1] + bf2f((u16)px1) + bs1;
    float go = g[2] + bf2f((u16)px2) + bs2;
    float gc = g[3] + bf2f((u16)px3) + bs3;
    float iv = 1.f / (1.f + __expf(-gi));
    float fv = 1.f / (1.f + __expf(-gf));
    float ov = 1.f / (1.f + __expf(-go));
    float cv = tanhf(gc);
    c_state = 1.f / (1.f + __expf(-(fv * c_state + iv * cv)));  // nonstandard, per reference
    float hn = tanhf(c_state) * ov;

    if (t == T_LEN - 1) {
      out[(size_t)hrow * 1024 + hcol] = hn;
    } else {
      // h store (write-through)
      u16* hdst = hroll + (size_t)(t + 1) * 65536 + (size_t)hrow * 1024 + hcol;
      u32 hb = (u32)f2bf(hn);
      asm volatile("global_store_short %0, %1, off sc0 sc1" :: "v"(hdst), "v"(hb) : "memory");
      // gate: slab for step t+1 must be published (ramp-only in steady state)
      int tpn = (t + 1) >> 1;
      if (tpn >= ready_tp) {
        const u32* cp = cntx + (tpn & ~3);
        int q = tpn & 3;
        for (;;) {
          u32x4 c4;
          asm volatile("global_load_dwordx4 %0, %1, off sc0 sc1\n\ts_waitcnt vmcnt(0)"
                       : "=&v"(c4) : "v"(cp) : "memory");
          u32 v0 = c4[0], v1 = c4[1], v2 = c4[2], v3 = c4[3];
          bool b0 = v0 >= 32u, b1 = v1 >= 32u, b2 = v2 >= 32u, b3 = v3 >= 32u;
          bool mine = (q == 0) ? b0 : (q == 1) ? b1 : (q == 2) ? b2 : b3;
          if (mine) {
            int ext = (q == 0) ? (b1 ? (b2 ? (b3 ? 4 : 3) : 2) : 1)
                    : (q == 1) ? (b2 ? (b3 ? 3 : 2) : 1)
                    : (q == 2) ? (b3 ? 2 : 1) : 1;
            ready_tp = tpn + ext;
            break;
          }
        }
      }
      // xproj(t+1) prefetch (plain cached; lines virgin -> post-publish fills)
      const u16* xn0 = xpt + (size_t)(t + 1) * 262144;
      const u16* xn1 = xn0 + 65536;
      const u16* xn2 = xn0 + 131072;
      const u16* xn3 = xn0 + 196608;
      asm volatile(
          "global_load_ushort %0, %4, off\n\t"
          "global_load_ushort %1, %5, off\n\t"
          "global_load_ushort %2, %6, off\n\t"
          "global_load_ushort %3, %7, off"
          : "=&v"(px0), "=&v"(px1), "=&v"(px2), "=&v"(px3)
          : "v"(xn0), "v"(xn1), "v"(xn2), "v"(xn3)
          : "memory");
      // retire the h store (oldest VMEM op; 4 prefetch loads stay in flight)
      asm volatile("s_waitcnt vmcnt(4)" ::: "memory");
      __syncthreads();  // all 8 waves' stores drained; pacc reads done
      if (tid == 0) {
        u32 one = 1u;
        asm volatile("global_atomic_add %0, %1, off" :: "v"(cnt), "v"(one) : "memory");
        u32 tgt = (u32)((t + 1) << 6);  // 64 publishers per domain
        u32 f;
        for (;;) {
          asm volatile("global_load_dword %0, %1, off sc0 sc1\n\ts_waitcnt vmcnt(0)"
                       : "=&v"(f) : "v"(cnt) : "memory");
          if (f >= tgt) break;
        }
      }
      __syncthreads();
    }
  }
}

extern "C" void kernel_launch(void* const* d_in, const int* in_sizes, int n_in,
                              void* d_out, int out_size, void* d_ws, size_t ws_size,
                              hipStream_t stream) {
  const float* x  = (const float*)d_in[0];   // [512][64][1024]
  const float* Wx = (const float*)d_in[1];   // [4][1024][1024]
  const float* bx = (const float*)d_in[2];   // [4][1024]
  const float* Wh = (const float*)d_in[3];   // [4][1024][1024]
  const float* bh = (const float*)d_in[4];   // [4][1024]
  float* out = (float*)d_out;                // [64][1024]
  char* ws = (char*)d_ws;

  u16* wx_bf  = (u16*)(ws + OFF_WX);
  u16* wh_bf  = (u16*)(ws + OFF_WH);
  float* bias = (float*)(ws + OFF_BIAS);
  u32* flags  = (u32*)(ws + OFF_FLAGS);
  u16* hroll  = (u16*)(ws + OFF_HROLL);
  u16* x_bf   = (u16*)(ws + OFF_XBF);
  u16* xproj  = (u16*)(ws + OFF_XPROJ);

  // per-launch: zero barrier counters + slab counters (2 KiB) + hroll slot 0
  // (128 KiB) -- contiguous region
  hipMemsetAsync(ws + OFF_FLAGS, 0, 2048 + 131072, stream);

  cvt_f32_bf16<<<4096, 256, 0, stream>>>(Wx, wx_bf, 4194304);
  cvt_f32_bf16<<<4096, 256, 0, stream>>>(Wh, wh_bf, 4194304);
  bias_add<<<16, 256, 0, stream>>>(bx, bh, bias);
  cvt_f32_bf16<<<32768, 256, 0, stream>>>(x, x_bf, 33554432);
  lstm_fused<<<256, 512, 0, stream>>>(x_bf, wx_bf, xproj, wh_bf, bias, hroll, flags, out);
}